// Round 14
// baseline (108.937 us; speedup 1.0000x reference)
//
#include <hip/hip_runtime.h>
#include <hip/hip_bf16.h>
#include <stdint.h>

#define NN 100000
#define KN 50
#define FIN 128
#define FOUT 128
#define BM 32                // nodes per fused block (8 blocks/CU)
#define NCAST 12500          // NN*FIN/4/256
#define NPACK 16             // 4096 threads
#define NDET 32              // 8192 threads

typedef __attribute__((ext_vector_type(8))) short bf16x8;
typedef __attribute__((ext_vector_type(4))) float f32x4;
typedef __attribute__((ext_vector_type(2))) float f32x2;

__device__ __forceinline__ uint16_t f2b(float f){
  uint32_t x = __builtin_bit_cast(uint32_t, f);
  x += 0x7fffu + ((x >> 16) & 1u);   // round-to-nearest-even
  return (uint16_t)(x >> 16);
}

// ---- prep: cast x->fp8 | pack W->bf16 frags | detect idx layout, one launch ----
__global__ __launch_bounds__(256) void prep_kernel(
    const float* __restrict__ x, uint32_t* __restrict__ xf8,
    const float* __restrict__ w, uint16_t* __restrict__ wp,
    const int* __restrict__ nb, int* __restrict__ flag)
{
  const int b = blockIdx.x, tid = threadIdx.x;
  if (b < NCAST){
    int i = b * 256 + tid;                 // one u32 = 4 fp8
    float4 v = *(const float4*)(x + (size_t)i * 4);
    uint32_t p = 0;
    p = __builtin_amdgcn_cvt_pk_fp8_f32(v.x, v.y, p, false);
    p = __builtin_amdgcn_cvt_pk_fp8_f32(v.z, v.w, p, true);
    xf8[i] = p;
  } else if (b < NCAST + NPACK){
    int tp = (b - NCAST) * 256 + tid;      // 4096 = 64 tiles x 64 lanes
    int bb = tp >> 6, lane = tp & 63;
    int kt = bb >> 3, nt = bb & 7;
    int col = nt * 16 + (lane & 15);
    int k0  = kt * 32 + ((lane >> 4) << 3);
    uint16_t vals[8];
    #pragma unroll
    for (int i = 0; i < 8; i++) vals[i] = f2b(w[(k0 + i) * FOUT + col]);
    *(uint4*)(wp + ((size_t)(kt * 8 + nt) * 64 + lane) * 8) = *(const uint4*)vals;
  } else {
    int i = (b - NCAST - NPACK) * 256 + tid;   // 8192 odd words
    if (nb[2 * i + 1] != 0) *flag = 1;
  }
}

#define CVT8(ACC, v)                                           \
  ACC[0] += __builtin_amdgcn_cvt_pk_f32_fp8((v).x, false);     \
  ACC[1] += __builtin_amdgcn_cvt_pk_f32_fp8((v).x, true);      \
  ACC[2] += __builtin_amdgcn_cvt_pk_f32_fp8((v).y, false);     \
  ACC[3] += __builtin_amdgcn_cvt_pk_f32_fp8((v).y, true);      \
  ACC[4] += __builtin_amdgcn_cvt_pk_f32_fp8((v).z, false);     \
  ACC[5] += __builtin_amdgcn_cvt_pk_f32_fp8((v).z, true);      \
  ACC[6] += __builtin_amdgcn_cvt_pk_f32_fp8((v).w, false);     \
  ACC[7] += __builtin_amdgcn_cvt_pk_f32_fp8((v).w, true);

// ---- fused gather+mean+GEMM, BM=32, 256 thr: 8 independently-phased
// blocks/CU keep gather-request pressure at >=7/8 while any one block runs
// its GEMM/epilogue. Self-feature x loads issued at kernel start (T14).
__global__ __launch_bounds__(256, 8) void fused_kernel(
    const float* __restrict__ x,
    const uint8_t* __restrict__ xf8,
    const int* __restrict__ nbrs,
    const uint16_t* __restrict__ wp,
    const float* __restrict__ bias,
    const int* __restrict__ flag,
    float* __restrict__ out)
{
  __shared__ uint16_t h[BM][264];            // 16896 B
  int* idxs = (int*)&h[0][0];                // 6400 B aliased; dead before h written
  const int tid  = threadIdx.x;
  const int wave = tid >> 6, lane = tid & 63;  // 4 waves
  const int base = blockIdx.x * BM;
  const int sm = (*flag != 0) ? 1 : 2;       // int64: low dword at 2x index

  // phase 0: issue self-feature loads NOW; consumed in phase 3 (latency
  // hides under the whole gather phase).
  float4 sv[4];
  #pragma unroll
  for (int jj = 0; jj < 4; jj++){
    int ci = jj * 256 + tid;                 // 1024 float4 chunks (32 rows x 32)
    int r = ci >> 5, c = ci & 31;
    int node = base + r; if (node >= NN) node = NN - 1;
    sv[jj] = *(const float4*)(x + (size_t)node * FIN + c * 4);
  }

  // phase 1: each wave stages its 8 rows x 50 neighbor indices
  {
    long long fb = (long long)(base + wave * 8) * KN;
    const long long fcap = (long long)NN * KN - 1;
    for (int t = lane; t < 8 * KN; t += 64){
      long long f = fb + t; if (f > fcap) f = fcap;   // clamp OOB rows
      idxs[wave * 8 * KN + t] = nbrs[f * sm];
    }
  }
  __syncthreads();

  // phase 2: gather (request-rate-bound). 8-lane group g owns row wave*8+g.
  const int g  = lane >> 3;
  const int fl = (lane & 7) * 16;            // 16 fp8 features per lane
  const uint8_t* xfl = xf8 + fl;
  const int* ip = idxs + wave * 8 * KN + g * KN;

  f32x2 acc8[8];
  #pragma unroll
  for (int i = 0; i < 8; i++) acc8[i] = (f32x2){0.f, 0.f};

  #pragma unroll 10
  for (int k = 0; k < KN; k++){
    int j = ip[k];
    uint4 v = *(const uint4*)(xfl + ((size_t)(uint32_t)j << 7));
    CVT8(acc8, v);
  }

  __syncthreads();                           // idxs region dead from here

  // phase 3a: dump agg (bf16) into h[wave*8+g][128+fl..]
  {
    uint16_t o[16];
    #pragma unroll
    for (int i = 0; i < 8; i++){
      o[2*i]   = f2b(acc8[i].x * (1.0f / KN));
      o[2*i+1] = f2b(acc8[i].y * (1.0f / KN));
    }
    uint16_t* d = &h[wave * 8 + g][FIN + fl];
    *(uint4*)(d)     = *(const uint4*)(o);
    *(uint4*)(d + 8) = *(const uint4*)(o + 8);
  }

  // phase 3b: self features (already in sv registers) -> bf16 -> h[r][0..128)
  #pragma unroll
  for (int jj = 0; jj < 4; jj++){
    int ci = jj * 256 + tid;
    int r = ci >> 5, c = ci & 31;
    float4 v = sv[jj];
    ushort4 o2; o2.x = f2b(v.x); o2.y = f2b(v.y); o2.z = f2b(v.z); o2.w = f2b(v.w);
    *(ushort4*)(&h[r][c * 4]) = o2;
  }

  __syncthreads();

  // phase 4: GEMM. Wave w owns 32 output cols; B-frags from L1/L2-hot wp.
  f32x4 acc[2][2];
  #pragma unroll
  for (int mt = 0; mt < 2; mt++)
    for (int n = 0; n < 2; n++) acc[mt][n] = (f32x4){0.f, 0.f, 0.f, 0.f};

  const int arow = lane & 15;
  const int ak   = (lane >> 4) << 3;
  #pragma unroll
  for (int kt = 0; kt < 8; kt++){
    bf16x8 b0 = *(const bf16x8*)(wp + ((size_t)(kt * 8 + wave * 2)     * 64 + lane) * 8);
    bf16x8 b1 = *(const bf16x8*)(wp + ((size_t)(kt * 8 + wave * 2 + 1) * 64 + lane) * 8);
    #pragma unroll
    for (int mt = 0; mt < 2; mt++){
      bf16x8 af = *(const bf16x8*)(&h[mt * 16 + arow][kt * 32 + ak]);
      acc[mt][0] = __builtin_amdgcn_mfma_f32_16x16x32_bf16(af, b0, acc[mt][0], 0, 0, 0);
      acc[mt][1] = __builtin_amdgcn_mfma_f32_16x16x32_bf16(af, b1, acc[mt][1], 0, 0, 0);
    }
  }

  // phase 5: epilogue. C/D layout col=lane&15, row=(lane>>4)*4+i  [m89]
  #pragma unroll
  for (int ntl = 0; ntl < 2; ntl++){
    int col = wave * 32 + ntl * 16 + (lane & 15);
    float bv = bias[col];
    #pragma unroll
    for (int mt = 0; mt < 2; mt++){
      #pragma unroll
      for (int i = 0; i < 4; i++){
        int row = mt * 16 + ((lane >> 4) << 2) + i;
        int node = base + row;
        if (node < NN){
          float v = acc[mt][ntl][i] + bv;
          out[(size_t)node * FOUT + col] = fmaxf(v, 0.f);
        }
      }
    }
  }
}

extern "C" void kernel_launch(void* const* d_in, const int* in_sizes, int n_in,
                              void* d_out, int out_size, void* d_ws, size_t ws_size,
                              hipStream_t stream){
  const float* x    = (const float*)d_in[0];
  const int*   nbrs = (const int*)d_in[1];
  const float* w    = (const float*)d_in[2];
  const float* bias = (const float*)d_in[3];
  float* out = (float*)d_out;

  uint8_t*  xf8  = (uint8_t*)d_ws;                                   // 12.8 MB
  uint16_t* wp   = (uint16_t*)((char*)d_ws + (size_t)NN * FIN);      // 64 KB
  int*      flag = (int*)((char*)d_ws + (size_t)NN * FIN + 65536);

  (void)hipMemsetAsync(flag, 0, 4, stream);
  prep_kernel<<<NCAST + NPACK + NDET, 256, 0, stream>>>(
      x, (uint32_t*)xf8, w, wp, (const int*)nbrs, flag);
  fused_kernel<<<(NN + BM - 1) / BM, 256, 0, stream>>>(
      x, xf8, nbrs, wp, bias, flag, out);
}

// Round 15
// 107.650 us; speedup vs baseline: 1.0120x; 1.0120x over previous
//
#include <hip/hip_runtime.h>
#include <hip/hip_bf16.h>
#include <stdint.h>

#define NN 100000
#define KN 50
#define FIN 128
#define FOUT 128
#define BM 64
#define NCAST 12500          // NN*FIN/4/256
#define NPACK 16             // 4096 threads
#define NDET 32              // 8192 threads

typedef __attribute__((ext_vector_type(8))) short bf16x8;
typedef __attribute__((ext_vector_type(4))) float f32x4;
typedef __attribute__((ext_vector_type(2))) float f32x2;

__device__ __forceinline__ uint16_t f2b(float f){
  uint32_t x = __builtin_bit_cast(uint32_t, f);
  x += 0x7fffu + ((x >> 16) & 1u);   // round-to-nearest-even
  return (uint16_t)(x >> 16);
}

// ---- prep: cast x->fp8 | pack W->bf16 frags | detect idx layout, one launch ----
__global__ __launch_bounds__(256) void prep_kernel(
    const float* __restrict__ x, uint32_t* __restrict__ xf8,
    const float* __restrict__ w, uint16_t* __restrict__ wp,
    const int* __restrict__ nb, int* __restrict__ flag)
{
  const int b = blockIdx.x, tid = threadIdx.x;
  if (b < NCAST){
    int i = b * 256 + tid;                 // one u32 = 4 fp8
    float4 v = *(const float4*)(x + (size_t)i * 4);
    uint32_t p = 0;
    p = __builtin_amdgcn_cvt_pk_fp8_f32(v.x, v.y, p, false);
    p = __builtin_amdgcn_cvt_pk_fp8_f32(v.z, v.w, p, true);
    xf8[i] = p;
  } else if (b < NCAST + NPACK){
    int tp = (b - NCAST) * 256 + tid;      // 4096 = 64 tiles x 64 lanes
    int bb = tp >> 6, lane = tp & 63;
    int kt = bb >> 3, nt = bb & 7;
    int col = nt * 16 + (lane & 15);
    int k0  = kt * 32 + ((lane >> 4) << 3);
    uint16_t vals[8];
    #pragma unroll
    for (int i = 0; i < 8; i++) vals[i] = f2b(w[(k0 + i) * FOUT + col]);
    *(uint4*)(wp + ((size_t)(kt * 8 + nt) * 64 + lane) * 8) = *(const uint4*)vals;
  } else {
    int i = (b - NCAST - NPACK) * 256 + tid;   // 8192 odd words
    if (nb[2 * i + 1] != 0) *flag = 1;
  }
}

#define CVT8(ACC, v)                                           \
  ACC[0] += __builtin_amdgcn_cvt_pk_f32_fp8((v).x, false);     \
  ACC[1] += __builtin_amdgcn_cvt_pk_f32_fp8((v).x, true);      \
  ACC[2] += __builtin_amdgcn_cvt_pk_f32_fp8((v).y, false);     \
  ACC[3] += __builtin_amdgcn_cvt_pk_f32_fp8((v).y, true);      \
  ACC[4] += __builtin_amdgcn_cvt_pk_f32_fp8((v).z, false);     \
  ACC[5] += __builtin_amdgcn_cvt_pk_f32_fp8((v).z, true);      \
  ACC[6] += __builtin_amdgcn_cvt_pk_f32_fp8((v).w, false);     \
  ACC[7] += __builtin_amdgcn_cvt_pk_f32_fp8((v).w, true);

// ---- fused gather+mean+GEMM, BM=64, 8 waves/block: 4 blocks/CU = 32 waves/CU.
// Gather shape per wave == r4's proven-optimal (8 rows, 8-lane groups). Self-
// feature x loads issued in phase 0 (T14): latency hides under the gather.
__global__ __launch_bounds__(512, 8) void fused_kernel(
    const float* __restrict__ x,
    const uint8_t* __restrict__ xf8,
    const int* __restrict__ nbrs,
    const uint16_t* __restrict__ wp,
    const float* __restrict__ bias,
    const int* __restrict__ flag,
    float* __restrict__ out)
{
  __shared__ uint16_t h[BM][264];            // 33792 B
  int* idxs = (int*)&h[0][0];                // 12.8 KB aliased; dead before h written
  const int tid  = threadIdx.x;
  const int wave = tid >> 6, lane = tid & 63;  // 8 waves
  const int base = blockIdx.x * BM;
  const int sm = (*flag != 0) ? 1 : 2;       // int64: low dword at 2x index

  // phase 0: issue self-feature loads NOW; consumed in phase 3b (T14 —
  // ~500cy HBM latency + 51MB streaming hide under the 50-iter gather).
  float4 sv[4];
  #pragma unroll
  for (int jj = 0; jj < 4; jj++){
    int ci = jj * 512 + tid;                 // 2048 float4 chunks (64 rows x 32)
    int r = ci >> 5, c = ci & 31;
    int node = base + r; if (node >= NN) node = NN - 1;
    sv[jj] = *(const float4*)(x + (size_t)node * FIN + c * 4);
  }

  // phase 1: each wave stages its 8 rows x 50 neighbor indices
  {
    long long fb = (long long)(base + wave * 8) * KN;
    const long long fcap = (long long)NN * KN - 1;
    for (int t = lane; t < 8 * KN; t += 64){
      long long f = fb + t; if (f > fcap) f = fcap;   // clamp OOB rows
      idxs[wave * 8 * KN + t] = nbrs[f * sm];
    }
  }
  __syncthreads();

  // phase 2: gather (request-rate-bound). 8-lane group g owns row wave*8+g.
  const int g  = lane >> 3;
  const int fl = (lane & 7) * 16;            // 16 fp8 features per lane
  const uint8_t* xfl = xf8 + fl;
  const int* ip = idxs + wave * 8 * KN + g * KN;

  f32x2 acc8[8];
  #pragma unroll
  for (int i = 0; i < 8; i++) acc8[i] = (f32x2){0.f, 0.f};

  #pragma unroll 10
  for (int k = 0; k < KN; k++){
    int j = ip[k];
    uint4 v = *(const uint4*)(xfl + ((size_t)(uint32_t)j << 7));
    CVT8(acc8, v);
  }

  __syncthreads();                           // idxs region dead from here

  // phase 3a: dump agg (bf16) into h[wave*8+g][128+fl..]
  {
    uint16_t o[16];
    #pragma unroll
    for (int i = 0; i < 8; i++){
      o[2*i]   = f2b(acc8[i].x * (1.0f / KN));
      o[2*i+1] = f2b(acc8[i].y * (1.0f / KN));
    }
    uint16_t* d = &h[wave * 8 + g][FIN + fl];
    *(uint4*)(d)     = *(const uint4*)(o);
    *(uint4*)(d + 8) = *(const uint4*)(o + 8);
  }

  // phase 3b: self features (already in sv registers) -> bf16 -> h[r][0..128)
  #pragma unroll
  for (int jj = 0; jj < 4; jj++){
    int ci = jj * 512 + tid;
    int r = ci >> 5, c = ci & 31;
    float4 v = sv[jj];
    ushort4 o2; o2.x = f2b(v.x); o2.y = f2b(v.y); o2.z = f2b(v.z); o2.w = f2b(v.w);
    *(ushort4*)(&h[r][c * 4]) = o2;
  }

  __syncthreads();

  // phase 4: GEMM. Wave w owns 16 output cols (nt=w); B-frag loaded per kt
  // from L2-hot wp (keeps VGPR under the 64-reg/8-wave cap).
  f32x4 acc[4];
  #pragma unroll
  for (int mt = 0; mt < 4; mt++) acc[mt] = (f32x4){0.f, 0.f, 0.f, 0.f};

  const int arow = lane & 15;
  const int ak   = (lane >> 4) << 3;
  #pragma unroll
  for (int kt = 0; kt < 8; kt++){
    bf16x8 bfrk = *(const bf16x8*)(wp + ((size_t)(kt * 8 + wave) * 64 + lane) * 8);
    #pragma unroll
    for (int mt = 0; mt < 4; mt++){
      bf16x8 af = *(const bf16x8*)(&h[mt * 16 + arow][kt * 32 + ak]);
      acc[mt] = __builtin_amdgcn_mfma_f32_16x16x32_bf16(af, bfrk, acc[mt], 0, 0, 0);
    }
  }

  // phase 5: epilogue. C/D layout col=lane&15, row=(lane>>4)*4+i  [m89]
  {
    int col = wave * 16 + (lane & 15);
    float bv = bias[col];
    #pragma unroll
    for (int mt = 0; mt < 4; mt++){
      #pragma unroll
      for (int i = 0; i < 4; i++){
        int row = mt * 16 + ((lane >> 4) << 2) + i;
        int node = base + row;
        if (node < NN){
          float v = acc[mt][i] + bv;
          out[(size_t)node * FOUT + col] = fmaxf(v, 0.f);
        }
      }
    }
  }
}

extern "C" void kernel_launch(void* const* d_in, const int* in_sizes, int n_in,
                              void* d_out, int out_size, void* d_ws, size_t ws_size,
                              hipStream_t stream){
  const float* x    = (const float*)d_in[0];
  const int*   nbrs = (const int*)d_in[1];
  const float* w    = (const float*)d_in[2];
  const float* bias = (const float*)d_in[3];
  float* out = (float*)d_out;

  uint8_t*  xf8  = (uint8_t*)d_ws;                                   // 12.8 MB
  uint16_t* wp   = (uint16_t*)((char*)d_ws + (size_t)NN * FIN);      // 64 KB
  int*      flag = (int*)((char*)d_ws + (size_t)NN * FIN + 65536);

  (void)hipMemsetAsync(flag, 0, 4, stream);
  prep_kernel<<<NCAST + NPACK + NDET, 256, 0, stream>>>(
      x, (uint32_t*)xf8, w, wp, (const int*)nbrs, flag);
  fused_kernel<<<(NN + BM - 1) / BM, 512, 0, stream>>>(
      x, xf8, nbrs, wp, bias, flag, out);
}

// Round 16
// 105.157 us; speedup vs baseline: 1.0359x; 1.0237x over previous
//
#include <hip/hip_runtime.h>
#include <hip/hip_bf16.h>
#include <stdint.h>

#define NN 100000
#define KN 50
#define FIN 128
#define FOUT 128
#define BM 64
#define NCAST 12500          // NN*FIN/4/256
#define NPACK 16             // 4096 threads
#define NDET 32              // 8192 threads

typedef __attribute__((ext_vector_type(8))) short bf16x8;
typedef __attribute__((ext_vector_type(4))) float f32x4;
typedef __attribute__((ext_vector_type(2))) float f32x2;

__device__ __forceinline__ uint16_t f2b(float f){
  uint32_t x = __builtin_bit_cast(uint32_t, f);
  x += 0x7fffu + ((x >> 16) & 1u);   // round-to-nearest-even
  return (uint16_t)(x >> 16);
}

// ---- prep: cast x->fp8 | pack W->bf16 frags | detect idx layout, one launch ----
__global__ __launch_bounds__(256) void prep_kernel(
    const float* __restrict__ x, uint32_t* __restrict__ xf8,
    const float* __restrict__ w, uint16_t* __restrict__ wp,
    const int* __restrict__ nb, int* __restrict__ flag)
{
  const int b = blockIdx.x, tid = threadIdx.x;
  if (b < NCAST){
    int i = b * 256 + tid;                 // one u32 = 4 fp8
    float4 v = *(const float4*)(x + (size_t)i * 4);
    uint32_t p = 0;
    p = __builtin_amdgcn_cvt_pk_fp8_f32(v.x, v.y, p, false);
    p = __builtin_amdgcn_cvt_pk_fp8_f32(v.z, v.w, p, true);
    xf8[i] = p;
  } else if (b < NCAST + NPACK){
    int tp = (b - NCAST) * 256 + tid;      // 4096 = 64 tiles x 64 lanes
    int bb = tp >> 6, lane = tp & 63;
    int kt = bb >> 3, nt = bb & 7;
    int col = nt * 16 + (lane & 15);
    int k0  = kt * 32 + ((lane >> 4) << 3);
    uint16_t vals[8];
    #pragma unroll
    for (int i = 0; i < 8; i++) vals[i] = f2b(w[(k0 + i) * FOUT + col]);
    *(uint4*)(wp + ((size_t)(kt * 8 + nt) * 64 + lane) * 8) = *(const uint4*)vals;
  } else {
    int i = (b - NCAST - NPACK) * 256 + tid;   // 8192 odd words
    if (nb[2 * i + 1] != 0) *flag = 1;
  }
}

#define CVT8(ACC, v)                                           \
  ACC[0] += __builtin_amdgcn_cvt_pk_f32_fp8((v).x, false);     \
  ACC[1] += __builtin_amdgcn_cvt_pk_f32_fp8((v).x, true);      \
  ACC[2] += __builtin_amdgcn_cvt_pk_f32_fp8((v).y, false);     \
  ACC[3] += __builtin_amdgcn_cvt_pk_f32_fp8((v).y, true);      \
  ACC[4] += __builtin_amdgcn_cvt_pk_f32_fp8((v).z, false);     \
  ACC[5] += __builtin_amdgcn_cvt_pk_f32_fp8((v).z, true);      \
  ACC[6] += __builtin_amdgcn_cvt_pk_f32_fp8((v).w, false);     \
  ACC[7] += __builtin_amdgcn_cvt_pk_f32_fp8((v).w, true);

// ---- fused gather+mean+GEMM, BM=64, 8 waves/block: 4 blocks/CU = 32 waves/CU.
// Gather shape per wave == r4's proven-optimal (8 rows, 8-lane groups). GEMM
// runs in the gather stall shadow of co-resident blocks (best-measured r13).
__global__ __launch_bounds__(512, 8) void fused_kernel(
    const float* __restrict__ x,
    const uint8_t* __restrict__ xf8,
    const int* __restrict__ nbrs,
    const uint16_t* __restrict__ wp,
    const float* __restrict__ bias,
    const int* __restrict__ flag,
    float* __restrict__ out)
{
  __shared__ uint16_t h[BM][264];            // 33792 B
  int* idxs = (int*)&h[0][0];                // 12.8 KB aliased; dead before h written
  const int tid  = threadIdx.x;
  const int wave = tid >> 6, lane = tid & 63;  // 8 waves
  const int base = blockIdx.x * BM;
  const int sm = (*flag != 0) ? 1 : 2;       // int64: low dword at 2x index

  // phase 1: each wave stages its 8 rows x 50 neighbor indices
  {
    long long fb = (long long)(base + wave * 8) * KN;
    const long long fcap = (long long)NN * KN - 1;
    for (int t = lane; t < 8 * KN; t += 64){
      long long f = fb + t; if (f > fcap) f = fcap;   // clamp OOB rows
      idxs[wave * 8 * KN + t] = nbrs[f * sm];
    }
  }
  __syncthreads();

  // phase 2: gather (request-rate-bound). 8-lane group g owns row wave*8+g.
  const int g  = lane >> 3;
  const int fl = (lane & 7) * 16;            // 16 fp8 features per lane
  const uint8_t* xfl = xf8 + fl;
  const int* ip = idxs + wave * 8 * KN + g * KN;

  f32x2 acc8[8];
  #pragma unroll
  for (int i = 0; i < 8; i++) acc8[i] = (f32x2){0.f, 0.f};

  #pragma unroll 10
  for (int k = 0; k < KN; k++){
    int j = ip[k];
    uint4 v = *(const uint4*)(xfl + ((size_t)(uint32_t)j << 7));
    CVT8(acc8, v);
  }

  __syncthreads();                           // idxs region dead from here

  // phase 3a: dump agg (bf16) into h[wave*8+g][128+fl..]
  {
    uint16_t o[16];
    #pragma unroll
    for (int i = 0; i < 8; i++){
      o[2*i]   = f2b(acc8[i].x * (1.0f / KN));
      o[2*i+1] = f2b(acc8[i].y * (1.0f / KN));
    }
    uint16_t* d = &h[wave * 8 + g][FIN + fl];
    *(uint4*)(d)     = *(const uint4*)(o);
    *(uint4*)(d + 8) = *(const uint4*)(o + 8);
  }

  // phase 3b: self features x fp32 -> bf16 -> h[r][0..128) (cooperative, 512 thr)
  #pragma unroll
  for (int jj = 0; jj < 4; jj++){
    int ci = jj * 512 + tid;                 // 2048 float4 chunks
    int r = ci >> 5, c = ci & 31;
    int node = base + r; if (node >= NN) node = NN - 1;
    float4 v = *(const float4*)(x + (size_t)node * FIN + c * 4);
    ushort4 o2; o2.x = f2b(v.x); o2.y = f2b(v.y); o2.z = f2b(v.z); o2.w = f2b(v.w);
    *(ushort4*)(&h[r][c * 4]) = o2;
  }

  __syncthreads();

  // phase 4: GEMM. Wave w owns 16 output cols (nt=w); B-frag loaded per kt
  // from L2-hot wp (keeps VGPR under the 64-reg/8-wave cap).
  f32x4 acc[4];
  #pragma unroll
  for (int mt = 0; mt < 4; mt++) acc[mt] = (f32x4){0.f, 0.f, 0.f, 0.f};

  const int arow = lane & 15;
  const int ak   = (lane >> 4) << 3;
  #pragma unroll
  for (int kt = 0; kt < 8; kt++){
    bf16x8 bfrk = *(const bf16x8*)(wp + ((size_t)(kt * 8 + wave) * 64 + lane) * 8);
    #pragma unroll
    for (int mt = 0; mt < 4; mt++){
      bf16x8 af = *(const bf16x8*)(&h[mt * 16 + arow][kt * 32 + ak]);
      acc[mt] = __builtin_amdgcn_mfma_f32_16x16x32_bf16(af, bfrk, acc[mt], 0, 0, 0);
    }
  }

  // phase 5: epilogue. C/D layout col=lane&15, row=(lane>>4)*4+i  [m89]
  {
    int col = wave * 16 + (lane & 15);
    float bv = bias[col];
    #pragma unroll
    for (int mt = 0; mt < 4; mt++){
      #pragma unroll
      for (int i = 0; i < 4; i++){
        int row = mt * 16 + ((lane >> 4) << 2) + i;
        int node = base + row;
        if (node < NN){
          float v = acc[mt][i] + bv;
          out[(size_t)node * FOUT + col] = fmaxf(v, 0.f);
        }
      }
    }
  }
}

extern "C" void kernel_launch(void* const* d_in, const int* in_sizes, int n_in,
                              void* d_out, int out_size, void* d_ws, size_t ws_size,
                              hipStream_t stream){
  const float* x    = (const float*)d_in[0];
  const int*   nbrs = (const int*)d_in[1];
  const float* w    = (const float*)d_in[2];
  const float* bias = (const float*)d_in[3];
  float* out = (float*)d_out;

  uint8_t*  xf8  = (uint8_t*)d_ws;                                   // 12.8 MB
  uint16_t* wp   = (uint16_t*)((char*)d_ws + (size_t)NN * FIN);      // 64 KB
  int*      flag = (int*)((char*)d_ws + (size_t)NN * FIN + 65536);

  (void)hipMemsetAsync(flag, 0, 4, stream);
  prep_kernel<<<NCAST + NPACK + NDET, 256, 0, stream>>>(
      x, (uint32_t*)xf8, w, wp, (const int*)nbrs, flag);
  fused_kernel<<<(NN + BM - 1) / BM, 512, 0, stream>>>(
      x, xf8, nbrs, wp, bias, flag, out);
}